// Round 2
// baseline (214.042 us; speedup 1.0000x reference)
//
#include <hip/hip_runtime.h>

// Problem constants (from reference): B=16, T=2048, L=1024, D=512, K=5
#define ROWS   (16 * 2048)   // B*T
#define ROWLEN 1024          // L
#define DMODEL 512           // D

// Math (mean-over-L of K=5 same-pad conv collapses to):
// out[row,d] = (Aw[d]*s - w0[d]*x[L-2] - (w0+w1)[d]*x[L-1]
//               - (w3+w4)[d]*x[0] - w4[d]*x[1]) / L + b[d]
// where s = sum of the row.

__global__ __launch_bounds__(256, 4) void conv1d_token_encoder_kernel(
    const float* __restrict__ x,
    const float* __restrict__ w,
    const float* __restrict__ b,
    float* __restrict__ out)
{
    __shared__ float cf[6][DMODEL];   // 12 KB derived coefficients

    const int tid    = threadIdx.x;
    const int lane   = tid & 63;
    const int wid    = blockIdx.x * 4 + (tid >> 6);
    const int nwaves = gridDim.x * 4;
    const float invL = 1.0f / (float)ROWLEN;   // exact (power of two)

    // ---- cooperative coefficient build, once per block ----
    // thread t handles channels t and t+256: 20 B contiguous per thread,
    // block covers the whole 10 KB w table (L2-resident) coalesced-ish.
#pragma unroll
    for (int g = 0; g < 2; ++g) {
        const int d = tid + g * 256;
        const float w0 = w[d * 5 + 0];
        const float w1 = w[d * 5 + 1];
        const float w2 = w[d * 5 + 2];
        const float w3 = w[d * 5 + 3];
        const float w4 = w[d * 5 + 4];
        cf[0][d] = (w0 + w1 + w2 + w3 + w4) * invL;
        cf[1][d] = w0 * invL;
        cf[2][d] = (w0 + w1) * invL;
        cf[3][d] = (w3 + w4) * invL;
        cf[4][d] = w4 * invL;
        cf[5][d] = b[d];
    }
    __syncthreads();

    // per-lane coefficient registers: channels d = 4*lane + 256*j + c
    float4 A[2], M2[2], M1[2], C0[2], C1[2], Bb[2];
#pragma unroll
    for (int j = 0; j < 2; ++j) {
        const int d = 4 * lane + 256 * j;
        A[j]  = *(const float4*)&cf[0][d];
        M2[j] = *(const float4*)&cf[1][d];
        M1[j] = *(const float4*)&cf[2][d];
        C0[j] = *(const float4*)&cf[3][d];
        C1[j] = *(const float4*)&cf[4][d];
        Bb[j] = *(const float4*)&cf[5][d];
    }

    // ---- row loop: 2 rows per iteration, all 8 loads issued up front ----
    for (int row = 2 * wid; row < ROWS; row += 2 * nwaves) {
        const float4* __restrict__ xr0 = (const float4*)(x + (size_t)row * ROWLEN);
        const float4* __restrict__ xr1 = (const float4*)(x + (size_t)(row + 1) * ROWLEN);
        float4 a0 = xr0[lane];
        float4 a1 = xr0[lane + 64];
        float4 a2 = xr0[lane + 128];
        float4 a3 = xr0[lane + 192];
        float4 b0 = xr1[lane];
        float4 b1 = xr1[lane + 64];
        float4 b2 = xr1[lane + 128];
        float4 b3 = xr1[lane + 192];

        float s0 = (a0.x + a0.y + a0.z + a0.w) + (a1.x + a1.y + a1.z + a1.w)
                 + (a2.x + a2.y + a2.z + a2.w) + (a3.x + a3.y + a3.z + a3.w);
        float s1 = (b0.x + b0.y + b0.z + b0.w) + (b1.x + b1.y + b1.z + b1.w)
                 + (b2.x + b2.y + b2.z + b2.w) + (b3.x + b3.y + b3.z + b3.w);
        // two independent butterfly chains -> ILP 2
#pragma unroll
        for (int m = 1; m < 64; m <<= 1) {
            s0 += __shfl_xor(s0, m, 64);
            s1 += __shfl_xor(s1, m, 64);
        }

        const float x0_0  = __shfl(a0.x, 0, 64);
        const float x1_0  = __shfl(a0.y, 0, 64);
        const float xm2_0 = __shfl(a3.z, 63, 64);
        const float xm1_0 = __shfl(a3.w, 63, 64);
        const float x0_1  = __shfl(b0.x, 0, 64);
        const float x1_1  = __shfl(b0.y, 0, 64);
        const float xm2_1 = __shfl(b3.z, 63, 64);
        const float xm1_1 = __shfl(b3.w, 63, 64);

        float4* __restrict__ o0 = (float4*)(out + (size_t)row * DMODEL);
        float4* __restrict__ o1 = (float4*)(out + (size_t)(row + 1) * DMODEL);
#pragma unroll
        for (int j = 0; j < 2; ++j) {
            float4 t;
            t.x = A[j].x * s0 - M2[j].x * xm2_0 - M1[j].x * xm1_0
                - C0[j].x * x0_0 - C1[j].x * x1_0 + Bb[j].x;
            t.y = A[j].y * s0 - M2[j].y * xm2_0 - M1[j].y * xm1_0
                - C0[j].y * x0_0 - C1[j].y * x1_0 + Bb[j].y;
            t.z = A[j].z * s0 - M2[j].z * xm2_0 - M1[j].z * xm1_0
                - C0[j].z * x0_0 - C1[j].z * x1_0 + Bb[j].z;
            t.w = A[j].w * s0 - M2[j].w * xm2_0 - M1[j].w * xm1_0
                - C0[j].w * x0_0 - C1[j].w * x1_0 + Bb[j].w;
            o0[lane + 64 * j] = t;

            t.x = A[j].x * s1 - M2[j].x * xm2_1 - M1[j].x * xm1_1
                - C0[j].x * x0_1 - C1[j].x * x1_1 + Bb[j].x;
            t.y = A[j].y * s1 - M2[j].y * xm2_1 - M1[j].y * xm1_1
                - C0[j].y * x0_1 - C1[j].y * x1_1 + Bb[j].y;
            t.z = A[j].z * s1 - M2[j].z * xm2_1 - M1[j].z * xm1_1
                - C0[j].z * x0_1 - C1[j].z * x1_1 + Bb[j].z;
            t.w = A[j].w * s1 - M2[j].w * xm2_1 - M1[j].w * xm1_1
                - C0[j].w * x0_1 - C1[j].w * x1_1 + Bb[j].w;
            o1[lane + 64 * j] = t;
        }
    }
}

extern "C" void kernel_launch(void* const* d_in, const int* in_sizes, int n_in,
                              void* d_out, int out_size, void* d_ws, size_t ws_size,
                              hipStream_t stream) {
    const float* x = (const float*)d_in[0];  // [B,T,L] fp32
    const float* w = (const float*)d_in[1];  // [D,K]  fp32
    const float* b = (const float*)d_in[2];  // [D]    fp32
    float* out = (float*)d_out;              // [B,T,D] fp32

    // 1024 blocks x 4 waves = 4096 waves; 32768 rows -> 8 rows/wave (4 iters x 2)
    conv1d_token_encoder_kernel<<<1024, 256, 0, stream>>>(x, w, b, out);
}